// Round 5
// baseline (887.640 us; speedup 1.0000x reference)
//
#include <hip/hip_runtime.h>
#include <hip/hip_bf16.h>

// N=50000, E=1600000, F0=256, F1=256, F2=128
// R4 bottleneck: agg1 106us — random 512B-row gathers from 25.6MB h1 spill
// each XCD's 4MB L2 (FETCH 360MB at ~3.4TB/s on the L2-miss path).
// R5: column-sliced aggregation. A 32-col slice of h is 50000*64B = 3.2MB,
// L2-resident per XCD. blockIdx%8==g -> XCD g handles slice g for all nodes
// (F=256: 8 slices; F=128: 4 slices x 2 node-halves). Gathers become 64B
// L2-hit lines; edge list re-swept once per slice (sequential, cheap).

typedef __bf16 bf16x8 __attribute__((ext_vector_type(8)));
typedef float f32x4 __attribute__((ext_vector_type(4)));

__device__ inline unsigned short f2bf(float f) {
    unsigned u = __float_as_uint(f);
    u += 0x7FFFu + ((u >> 16) & 1u);  // RNE
    return (unsigned short)(u >> 16);
}
__device__ inline float bf16lo(unsigned q) { return __uint_as_float(q << 16); }
__device__ inline float bf16hi(unsigned q) { return __uint_as_float(q & 0xFFFF0000u); }

// ---------------- CSR build (XCD-partitioned, from R3) ----------------

#define XCDS 8

__global__ __launch_bounds__(256) void count_kernel_x(const int* __restrict__ dst,
                                                      int* __restrict__ cnt, int E, int ng) {
    int g = blockIdx.x & (XCDS - 1);
    int lo = g * ng, hi = lo + ng;
    int bid = blockIdx.x >> 3;
    int stride = (gridDim.x >> 3) * 256;
    for (int e = bid * 256 + threadIdx.x; e < E; e += stride) {
        int d = dst[e];
        if (d >= lo && d < hi) atomicAdd(&cnt[d], 1);
    }
}

__global__ __launch_bounds__(256) void place_kernel_x(const int* __restrict__ src,
                                                      const int* __restrict__ dst,
                                                      int* __restrict__ cursor,
                                                      int* __restrict__ ssrc, int E, int ng) {
    int g = blockIdx.x & (XCDS - 1);
    int lo = g * ng, hi = lo + ng;
    int bid = blockIdx.x >> 3;
    int stride = (gridDim.x >> 3) * 256;
    for (int e = bid * 256 + threadIdx.x; e < E; e += stride) {
        int d = dst[e];
        if (d >= lo && d < hi) {
            int p = atomicAdd(&cursor[d], 1);
            ssrc[p] = src[e];
        }
    }
}

__global__ void scan_kernel(const int* __restrict__ cnt, int* __restrict__ offs, int n) {
    __shared__ int s[256];
    int carry = 0;
    if (threadIdx.x == 0) offs[0] = 0;
    for (int base = 0; base < n; base += 1024) {
        int i0 = base + threadIdx.x * 4;
        int v[4];
#pragma unroll
        for (int j = 0; j < 4; ++j) v[j] = (i0 + j < n) ? cnt[i0 + j] : 0;
        int lsum = v[0] + v[1] + v[2] + v[3];
        s[threadIdx.x] = lsum;
        __syncthreads();
        for (int off = 1; off < 256; off <<= 1) {
            int t = (threadIdx.x >= off) ? s[threadIdx.x - off] : 0;
            __syncthreads();
            s[threadIdx.x] += t;
            __syncthreads();
        }
        int run = s[threadIdx.x] - lsum + carry;
#pragma unroll
        for (int j = 0; j < 4; ++j) {
            run += v[j];
            if (i0 + j < n) offs[i0 + j + 1] = run;
        }
        carry += s[255];
        __syncthreads();
    }
}

__global__ void dinv_cursor_kernel(const int* __restrict__ cnt, const int* __restrict__ offs,
                                   float* __restrict__ dinv, int* __restrict__ cursor, int n) {
    int i = blockIdx.x * 256 + threadIdx.x;
    if (i < n) {
        dinv[i] = rsqrtf((float)(cnt[i] + 1));
        cursor[i] = offs[i];
    }
}

// ---------------- casts ----------------

__global__ __launch_bounds__(256) void cast_bf16_kernel(const float* __restrict__ in,
                                                        unsigned short* __restrict__ out, int n) {
    int i = (blockIdx.x * 256 + threadIdx.x) * 8;
    if (i >= n) return;
    float4 a = *(const float4*)&in[i];
    float4 b = *(const float4*)&in[i + 4];
    uint4 p;
    p.x = (unsigned)f2bf(a.x) | ((unsigned)f2bf(a.y) << 16);
    p.y = (unsigned)f2bf(a.z) | ((unsigned)f2bf(a.w) << 16);
    p.z = (unsigned)f2bf(b.x) | ((unsigned)f2bf(b.y) << 16);
    p.w = (unsigned)f2bf(b.z) | ((unsigned)f2bf(b.w) << 16);
    *(uint4*)&out[i] = p;
}

__global__ void transpose_cast_kernel(const float* __restrict__ W,
                                      unsigned short* __restrict__ Wt, int K, int N) {
    int n = blockIdx.x;
    for (int k = threadIdx.x; k < K; k += 64)
        Wt[(size_t)n * K + k] = f2bf(W[(size_t)k * N + n]);
}

// ---------------- bf16 MFMA GEMM (from R4): C[M,N] = A @ Bt^T, bf16 out ----------------

template <int BN>
__global__ __launch_bounds__(256) void gemm_mfma_kernel(const unsigned short* __restrict__ A,
                                                        const unsigned short* __restrict__ Bt,
                                                        unsigned short* __restrict__ C,
                                                        int M, int K, int N) {
    constexpr int BM = 128, BK = 32, LDA = BK + 8;
    constexpr int CT = BN / 16;
    __shared__ unsigned short As[BM][LDA];
    __shared__ unsigned short Bs[BN][LDA];
    int tid = threadIdx.x;
    int wave = tid >> 6, lane = tid & 63;
    int quad = lane >> 4, l16 = lane & 15;
    int row0 = blockIdx.x * BM, col0 = blockIdx.y * BN;

    f32x4 acc[2][CT];
#pragma unroll
    for (int i = 0; i < 2; ++i)
#pragma unroll
        for (int j = 0; j < CT; ++j) acc[i][j] = (f32x4){0.f, 0.f, 0.f, 0.f};

    int ar = tid >> 2;
    int ac = (tid & 3) * 8;

    for (int k0 = 0; k0 < K; k0 += BK) {
#pragma unroll
        for (int i = 0; i < 2; ++i) {
            int r = ar + i * 64;
            int gr = row0 + r;
            uint4 v = make_uint4(0u, 0u, 0u, 0u);
            if (gr < M) v = *(const uint4*)&A[(size_t)gr * K + k0 + ac];
            *(uint4*)&As[r][ac] = v;
        }
#pragma unroll
        for (int i = 0; i < BN / 64; ++i) {
            int r = ar + i * 64;
            *(uint4*)&Bs[r][ac] = *(const uint4*)&Bt[(size_t)(col0 + r) * K + k0 + ac];
        }
        __syncthreads();
        bf16x8 af[2];
#pragma unroll
        for (int tr = 0; tr < 2; ++tr)
            af[tr] = *(const bf16x8*)&As[wave * 32 + tr * 16 + l16][quad * 8];
#pragma unroll
        for (int tc = 0; tc < CT; ++tc) {
            bf16x8 bf = *(const bf16x8*)&Bs[tc * 16 + l16][quad * 8];
            acc[0][tc] = __builtin_amdgcn_mfma_f32_16x16x32_bf16(af[0], bf, acc[0][tc], 0, 0, 0);
            acc[1][tc] = __builtin_amdgcn_mfma_f32_16x16x32_bf16(af[1], bf, acc[1][tc], 0, 0, 0);
        }
        __syncthreads();
    }
#pragma unroll
    for (int tr = 0; tr < 2; ++tr) {
        int gr0 = row0 + wave * 32 + tr * 16 + quad * 4;
#pragma unroll
        for (int tc = 0; tc < CT; ++tc) {
            int gc = col0 + tc * 16 + l16;
#pragma unroll
            for (int j = 0; j < 4; ++j) {
                int gr = gr0 + j;
                if (gr < M) C[(size_t)gr * N + gc] = f2bf(acc[tr][tc][j]);
            }
        }
    }
}

// ---------------- column-sliced aggregation ----------------
// One wave per (node, 32-col slice). blockIdx%8 = g -> XCD g; slice sl = g%NS,
// node-half = g/NS. Lane layout: grp=lane>>4 processes edges e0+grp, e0+grp+4,...
// lane&15 -> col pair (uint = 2 bf16, 16 lanes * 4B = one 64B line per gather).
// Butterfly-reduce over the 4 edge slots; lanes 0-15 write the 32-col result.

template <int F, bool RELU, typename OT>
__global__ __launch_bounds__(256) void agg_slice_kernel(const unsigned short* __restrict__ h,
                                                        const float* __restrict__ dinv,
                                                        const int* __restrict__ offs,
                                                        const int* __restrict__ ssrc,
                                                        const float* __restrict__ bias,
                                                        OT* __restrict__ out, int N) {
    constexpr int NS = F / 32;        // 8 (F=256) or 4 (F=128)
    constexpr int HALVES = 8 / NS;    // 1 or 2
    int g = blockIdx.x & 7;
    int sl = g % NS;
    int half = g / NS;
    int nodes_per = N / HALVES;       // 50000 or 25000
    int wave = threadIdx.x >> 6, lane = threadIdx.x & 63;
    int n = half * nodes_per + (int)(blockIdx.x >> 3) * 4 + wave;
    int nEnd = (half + 1) * nodes_per;
    if (half == HALVES - 1) nEnd = N;
    if (n >= nEnd) return;

    int grp = lane >> 4;              // edge slot 0..3
    int c = sl * 32 + (lane & 15) * 2;  // absolute column (even)
    float di = dinv[n];
    float a0 = 0.f, a1 = 0.f;

    if (grp == 0) {  // self loop
        unsigned q = *(const unsigned*)&h[(size_t)n * F + c];
        a0 = di * bf16lo(q);
        a1 = di * bf16hi(q);
    }

    int e1 = offs[n + 1];
    for (int e = offs[n] + grp; e < e1; e += 4) {
        int s = ssrc[e];
        float w = dinv[s];
        unsigned q = *(const unsigned*)&h[(size_t)s * F + c];
        a0 = fmaf(w, bf16lo(q), a0);
        a1 = fmaf(w, bf16hi(q), a1);
    }

    a0 += __shfl_xor(a0, 16); a1 += __shfl_xor(a1, 16);
    a0 += __shfl_xor(a0, 32); a1 += __shfl_xor(a1, 32);

    if (lane < 16) {
        float r0 = fmaf(a0, di, bias[c]);
        float r1 = fmaf(a1, di, bias[c + 1]);
        if (RELU) { r0 = fmaxf(r0, 0.f); r1 = fmaxf(r1, 0.f); }
        if constexpr (sizeof(OT) == 2) {
            unsigned p = (unsigned)f2bf(r0) | ((unsigned)f2bf(r1) << 16);
            *(unsigned*)&out[(size_t)n * F + c] = p;
        } else {
            *(float2*)&out[(size_t)n * F + c] = make_float2(r0, r1);
        }
    }
}

// ---------------- launch ----------------

extern "C" void kernel_launch(void* const* d_in, const int* in_sizes, int n_in,
                              void* d_out, int out_size, void* d_ws, size_t ws_size,
                              hipStream_t stream) {
    const float* x  = (const float*)d_in[0];
    const int*   ei = (const int*)d_in[1];
    const float* W1 = (const float*)d_in[2];
    const float* b1 = (const float*)d_in[3];
    const float* W2 = (const float*)d_in[4];
    const float* b2 = (const float*)d_in[5];
    float* out = (float*)d_out;

    const int F0 = 256, F1 = 256, F2 = 128;
    const int N = in_sizes[0] / F0;   // 50000
    const int E = in_sizes[1] / 2;    // 1600000
    const int* src = ei;
    const int* dst = ei + E;
    const int ng = (N + XCDS - 1) / XCDS;

    char* ws = (char*)d_ws;
    size_t off = 0;
    auto alloc = [&](size_t bytes) {
        char* p = ws + off;
        off += (bytes + 255) & ~(size_t)255;
        return p;
    };
    int*            cnt    = (int*)alloc((size_t)N * 4);
    int*            offs   = (int*)alloc((size_t)(N + 1) * 4);
    int*            cursor = (int*)alloc((size_t)N * 4);
    float*          dinv   = (float*)alloc((size_t)N * 4);
    int*            ssrc   = (int*)alloc((size_t)E * 4);
    unsigned short* xb     = (unsigned short*)alloc((size_t)N * F0 * 2);
    unsigned short* wt1    = (unsigned short*)alloc((size_t)F1 * F0 * 2);
    unsigned short* wt2    = (unsigned short*)alloc((size_t)F2 * F1 * 2);
    unsigned short* h1     = (unsigned short*)alloc((size_t)N * F1 * 2);
    unsigned short* h1a    = (unsigned short*)alloc((size_t)N * F1 * 2);
    unsigned short* h2     = (unsigned short*)alloc((size_t)N * F2 * 2);
    (void)ws_size; (void)n_in; (void)out_size;

    // CSR build
    hipMemsetAsync(cnt, 0, (size_t)N * 4, stream);
    count_kernel_x<<<2048, 256, 0, stream>>>(dst, cnt, E, ng);
    scan_kernel<<<1, 256, 0, stream>>>(cnt, offs, N);
    dinv_cursor_kernel<<<(N + 255) / 256, 256, 0, stream>>>(cnt, offs, dinv, cursor, N);
    place_kernel_x<<<2048, 256, 0, stream>>>(src, dst, cursor, ssrc, E, ng);

    // casts
    cast_bf16_kernel<<<(N * F0) / 2048, 256, 0, stream>>>(x, xb, N * F0);
    transpose_cast_kernel<<<F1, 64, 0, stream>>>(W1, wt1, F0, F1);
    transpose_cast_kernel<<<F2, 64, 0, stream>>>(W2, wt2, F1, F2);

    // layer 1
    {
        dim3 grid((N + 127) / 128, F1 / 128);
        gemm_mfma_kernel<128><<<grid, 256, 0, stream>>>(xb, wt1, h1, N, F0, F1);
    }
    {
        // F=256: 8 slices, full node range per slice; 4 nodes per block
        int blocks = ((N + 3) / 4) * 8;
        agg_slice_kernel<256, true, unsigned short><<<blocks, 256, 0, stream>>>(
            h1, dinv, offs, ssrc, b1, h1a, N);
    }

    // layer 2
    {
        dim3 grid((N + 127) / 128, F2 / 64);
        gemm_mfma_kernel<64><<<grid, 256, 0, stream>>>(h1a, wt2, h2, N, F1, F2);
    }
    {
        // F=128: 4 slices x 2 node halves
        int blocks = ((N / 2 + 4) / 4) * 8;
        agg_slice_kernel<128, false, float><<<blocks, 256, 0, stream>>>(
            h2, dinv, offs, ssrc, b2, out, N);
    }
}

// Round 6
// 533.423 us; speedup vs baseline: 1.6640x; 1.6640x over previous
//
#include <hip/hip_runtime.h>
#include <hip/hip_bf16.h>

// N=50000, E=1600000, F0=256, F1=256, F2=128
// R5 column-slice FAILED (352us vs 106): no L2 residency (FETCH unchanged) +
// MLP collapse (64B/group in flight). R6 = R4 row-gather agg with:
//  - wsrc[e]=dinv[src[e]] precomputed in place (kills dependent dinv load)
//  - 8-edge unroll, load-then-fma (8 independent 512B gathers in flight/wave)

typedef __bf16 bf16x8 __attribute__((ext_vector_type(8)));
typedef float f32x4 __attribute__((ext_vector_type(4)));

__device__ inline unsigned short f2bf(float f) {
    unsigned u = __float_as_uint(f);
    u += 0x7FFFu + ((u >> 16) & 1u);  // RNE
    return (unsigned short)(u >> 16);
}
__device__ inline float bf16lo(unsigned q) { return __uint_as_float(q << 16); }
__device__ inline float bf16hi(unsigned q) { return __uint_as_float(q & 0xFFFF0000u); }
__device__ inline void storev(float* p, float v) { *p = v; }
__device__ inline void storev(unsigned short* p, float v) { *p = f2bf(v); }

// ---------------- CSR build (XCD-partitioned) ----------------

#define XCDS 8

__global__ __launch_bounds__(256) void count_kernel_x(const int* __restrict__ dst,
                                                      int* __restrict__ cnt, int E, int ng) {
    int g = blockIdx.x & (XCDS - 1);
    int lo = g * ng, hi = lo + ng;
    int bid = blockIdx.x >> 3;
    int stride = (gridDim.x >> 3) * 256;
    for (int e = bid * 256 + threadIdx.x; e < E; e += stride) {
        int d = dst[e];
        if (d >= lo && d < hi) atomicAdd(&cnt[d], 1);
    }
}

__global__ __launch_bounds__(256) void place_kernel_x(const int* __restrict__ src,
                                                      const int* __restrict__ dst,
                                                      const float* __restrict__ dinv,
                                                      int* __restrict__ cursor,
                                                      int* __restrict__ ssrc,
                                                      float* __restrict__ wsrc, int E, int ng) {
    int g = blockIdx.x & (XCDS - 1);
    int lo = g * ng, hi = lo + ng;
    int bid = blockIdx.x >> 3;
    int stride = (gridDim.x >> 3) * 256;
    for (int e = bid * 256 + threadIdx.x; e < E; e += stride) {
        int d = dst[e];
        if (d >= lo && d < hi) {
            int s = src[e];
            int p = atomicAdd(&cursor[d], 1);
            ssrc[p] = s;
            wsrc[p] = dinv[s];
        }
    }
}

__global__ void scan_kernel(const int* __restrict__ cnt, int* __restrict__ offs, int n) {
    __shared__ int s[256];
    int carry = 0;
    if (threadIdx.x == 0) offs[0] = 0;
    for (int base = 0; base < n; base += 1024) {
        int i0 = base + threadIdx.x * 4;
        int v[4];
#pragma unroll
        for (int j = 0; j < 4; ++j) v[j] = (i0 + j < n) ? cnt[i0 + j] : 0;
        int lsum = v[0] + v[1] + v[2] + v[3];
        s[threadIdx.x] = lsum;
        __syncthreads();
        for (int off = 1; off < 256; off <<= 1) {
            int t = (threadIdx.x >= off) ? s[threadIdx.x - off] : 0;
            __syncthreads();
            s[threadIdx.x] += t;
            __syncthreads();
        }
        int run = s[threadIdx.x] - lsum + carry;
#pragma unroll
        for (int j = 0; j < 4; ++j) {
            run += v[j];
            if (i0 + j < n) offs[i0 + j + 1] = run;
        }
        carry += s[255];
        __syncthreads();
    }
}

__global__ void dinv_cursor_kernel(const int* __restrict__ cnt, const int* __restrict__ offs,
                                   float* __restrict__ dinv, int* __restrict__ cursor, int n) {
    int i = blockIdx.x * 256 + threadIdx.x;
    if (i < n) {
        dinv[i] = rsqrtf((float)(cnt[i] + 1));
        cursor[i] = offs[i];
    }
}

// ---------------- casts ----------------

__global__ __launch_bounds__(256) void cast_bf16_kernel(const float* __restrict__ in,
                                                        unsigned short* __restrict__ out, int n) {
    int i = (blockIdx.x * 256 + threadIdx.x) * 8;
    if (i >= n) return;
    float4 a = *(const float4*)&in[i];
    float4 b = *(const float4*)&in[i + 4];
    uint4 p;
    p.x = (unsigned)f2bf(a.x) | ((unsigned)f2bf(a.y) << 16);
    p.y = (unsigned)f2bf(a.z) | ((unsigned)f2bf(a.w) << 16);
    p.z = (unsigned)f2bf(b.x) | ((unsigned)f2bf(b.y) << 16);
    p.w = (unsigned)f2bf(b.z) | ((unsigned)f2bf(b.w) << 16);
    *(uint4*)&out[i] = p;
}

__global__ void transpose_cast_kernel(const float* __restrict__ W,
                                      unsigned short* __restrict__ Wt, int K, int N) {
    int n = blockIdx.x;
    for (int k = threadIdx.x; k < K; k += 64)
        Wt[(size_t)n * K + k] = f2bf(W[(size_t)k * N + n]);
}

// ---------------- bf16 MFMA GEMM: C[M,N] = A @ Bt^T, bf16 out ----------------

template <int BN>
__global__ __launch_bounds__(256) void gemm_mfma_kernel(const unsigned short* __restrict__ A,
                                                        const unsigned short* __restrict__ Bt,
                                                        unsigned short* __restrict__ C,
                                                        int M, int K, int N) {
    constexpr int BM = 128, BK = 32, LDA = BK + 8;
    constexpr int CT = BN / 16;
    __shared__ unsigned short As[BM][LDA];
    __shared__ unsigned short Bs[BN][LDA];
    int tid = threadIdx.x;
    int wave = tid >> 6, lane = tid & 63;
    int quad = lane >> 4, l16 = lane & 15;
    int row0 = blockIdx.x * BM, col0 = blockIdx.y * BN;

    f32x4 acc[2][CT];
#pragma unroll
    for (int i = 0; i < 2; ++i)
#pragma unroll
        for (int j = 0; j < CT; ++j) acc[i][j] = (f32x4){0.f, 0.f, 0.f, 0.f};

    int ar = tid >> 2;
    int ac = (tid & 3) * 8;

    for (int k0 = 0; k0 < K; k0 += BK) {
#pragma unroll
        for (int i = 0; i < 2; ++i) {
            int r = ar + i * 64;
            int gr = row0 + r;
            uint4 v = make_uint4(0u, 0u, 0u, 0u);
            if (gr < M) v = *(const uint4*)&A[(size_t)gr * K + k0 + ac];
            *(uint4*)&As[r][ac] = v;
        }
#pragma unroll
        for (int i = 0; i < BN / 64; ++i) {
            int r = ar + i * 64;
            *(uint4*)&Bs[r][ac] = *(const uint4*)&Bt[(size_t)(col0 + r) * K + k0 + ac];
        }
        __syncthreads();
        bf16x8 af[2];
#pragma unroll
        for (int tr = 0; tr < 2; ++tr)
            af[tr] = *(const bf16x8*)&As[wave * 32 + tr * 16 + l16][quad * 8];
#pragma unroll
        for (int tc = 0; tc < CT; ++tc) {
            bf16x8 bf = *(const bf16x8*)&Bs[tc * 16 + l16][quad * 8];
            acc[0][tc] = __builtin_amdgcn_mfma_f32_16x16x32_bf16(af[0], bf, acc[0][tc], 0, 0, 0);
            acc[1][tc] = __builtin_amdgcn_mfma_f32_16x16x32_bf16(af[1], bf, acc[1][tc], 0, 0, 0);
        }
        __syncthreads();
    }
#pragma unroll
    for (int tr = 0; tr < 2; ++tr) {
        int gr0 = row0 + wave * 32 + tr * 16 + quad * 4;
#pragma unroll
        for (int tc = 0; tc < CT; ++tc) {
            int gc = col0 + tc * 16 + l16;
#pragma unroll
            for (int j = 0; j < 4; ++j) {
                int gr = gr0 + j;
                if (gr < M) C[(size_t)gr * N + gc] = f2bf(acc[tr][tc][j]);
            }
        }
    }
}

// ---------------- aggregation: one wave per node, 8-edge unroll, load-then-fma ----------------

template <int F, bool RELU, typename OT>
__global__ __launch_bounds__(256) void agg_kernel(const unsigned short* __restrict__ h,
                                                  const float* __restrict__ dinv,
                                                  const int* __restrict__ offs,
                                                  const int* __restrict__ ssrc,
                                                  const float* __restrict__ wsrc,
                                                  const float* __restrict__ bias,
                                                  OT* __restrict__ out, int N) {
    constexpr int V = F / 64;  // 4 (F=256) or 2 (F=128)
    int n = blockIdx.x * 4 + (threadIdx.x >> 6);
    if (n >= N) return;
    int lane = threadIdx.x & 63;
    int c = lane * V;
    float di = dinv[n];
    float acc[V];

    // self loop
    {
        const unsigned short* p = h + (size_t)n * F + c;
        if constexpr (V == 4) {
            uint2 q = *(const uint2*)p;
            acc[0] = di * bf16lo(q.x); acc[1] = di * bf16hi(q.x);
            acc[2] = di * bf16lo(q.y); acc[3] = di * bf16hi(q.y);
        } else {
            unsigned q = *(const unsigned*)p;
            acc[0] = di * bf16lo(q); acc[1] = di * bf16hi(q);
        }
    }

    int e = offs[n], e1 = offs[n + 1];
    for (; e + 8 <= e1; e += 8) {
        int   s[8];
        float w[8];
#pragma unroll
        for (int j = 0; j < 8; ++j) s[j] = ssrc[e + j];
#pragma unroll
        for (int j = 0; j < 8; ++j) w[j] = wsrc[e + j];
        if constexpr (V == 4) {
            uint2 q[8];
#pragma unroll
            for (int j = 0; j < 8; ++j) q[j] = *(const uint2*)&h[(size_t)s[j] * F + c];
#pragma unroll
            for (int j = 0; j < 8; ++j) {
                acc[0] = fmaf(w[j], bf16lo(q[j].x), acc[0]);
                acc[1] = fmaf(w[j], bf16hi(q[j].x), acc[1]);
                acc[2] = fmaf(w[j], bf16lo(q[j].y), acc[2]);
                acc[3] = fmaf(w[j], bf16hi(q[j].y), acc[3]);
            }
        } else {
            unsigned q[8];
#pragma unroll
            for (int j = 0; j < 8; ++j) q[j] = *(const unsigned*)&h[(size_t)s[j] * F + c];
#pragma unroll
            for (int j = 0; j < 8; ++j) {
                acc[0] = fmaf(w[j], bf16lo(q[j]), acc[0]);
                acc[1] = fmaf(w[j], bf16hi(q[j]), acc[1]);
            }
        }
    }
    for (; e < e1; ++e) {
        int s = ssrc[e];
        float w = wsrc[e];
        const unsigned short* p = h + (size_t)s * F + c;
        if constexpr (V == 4) {
            uint2 q = *(const uint2*)p;
            acc[0] = fmaf(w, bf16lo(q.x), acc[0]);
            acc[1] = fmaf(w, bf16hi(q.x), acc[1]);
            acc[2] = fmaf(w, bf16lo(q.y), acc[2]);
            acc[3] = fmaf(w, bf16hi(q.y), acc[3]);
        } else {
            unsigned q = *(const unsigned*)p;
            acc[0] = fmaf(w, bf16lo(q), acc[0]);
            acc[1] = fmaf(w, bf16hi(q), acc[1]);
        }
    }

#pragma unroll
    for (int v = 0; v < V; ++v) {
        float r = fmaf(acc[v], di, bias[c + v]);
        if (RELU) r = fmaxf(r, 0.f);
        storev(&out[(size_t)n * F + c + v], r);
    }
}

// ---------------- launch ----------------

extern "C" void kernel_launch(void* const* d_in, const int* in_sizes, int n_in,
                              void* d_out, int out_size, void* d_ws, size_t ws_size,
                              hipStream_t stream) {
    const float* x  = (const float*)d_in[0];
    const int*   ei = (const int*)d_in[1];
    const float* W1 = (const float*)d_in[2];
    const float* b1 = (const float*)d_in[3];
    const float* W2 = (const float*)d_in[4];
    const float* b2 = (const float*)d_in[5];
    float* out = (float*)d_out;

    const int F0 = 256, F1 = 256, F2 = 128;
    const int N = in_sizes[0] / F0;   // 50000
    const int E = in_sizes[1] / 2;    // 1600000
    const int* src = ei;
    const int* dst = ei + E;
    const int ng = (N + XCDS - 1) / XCDS;

    char* ws = (char*)d_ws;
    size_t off = 0;
    auto alloc = [&](size_t bytes) {
        char* p = ws + off;
        off += (bytes + 255) & ~(size_t)255;
        return p;
    };
    int*            cnt    = (int*)alloc((size_t)N * 4);
    int*            offs   = (int*)alloc((size_t)(N + 1) * 4);
    int*            cursor = (int*)alloc((size_t)N * 4);
    float*          dinv   = (float*)alloc((size_t)N * 4);
    int*            ssrc   = (int*)alloc((size_t)E * 4);
    float*          wsrc   = (float*)alloc((size_t)E * 4);
    unsigned short* xb     = (unsigned short*)alloc((size_t)N * F0 * 2);
    unsigned short* wt1    = (unsigned short*)alloc((size_t)F1 * F0 * 2);
    unsigned short* wt2    = (unsigned short*)alloc((size_t)F2 * F1 * 2);
    unsigned short* h1     = (unsigned short*)alloc((size_t)N * F1 * 2);
    unsigned short* h1a    = (unsigned short*)alloc((size_t)N * F1 * 2);
    unsigned short* h2     = (unsigned short*)alloc((size_t)N * F2 * 2);
    (void)ws_size; (void)n_in; (void)out_size;

    // CSR build
    hipMemsetAsync(cnt, 0, (size_t)N * 4, stream);
    count_kernel_x<<<2048, 256, 0, stream>>>(dst, cnt, E, ng);
    scan_kernel<<<1, 256, 0, stream>>>(cnt, offs, N);
    dinv_cursor_kernel<<<(N + 255) / 256, 256, 0, stream>>>(cnt, offs, dinv, cursor, N);
    place_kernel_x<<<2048, 256, 0, stream>>>(src, dst, dinv, cursor, ssrc, wsrc, E, ng);

    // casts
    cast_bf16_kernel<<<(N * F0) / 2048, 256, 0, stream>>>(x, xb, N * F0);
    transpose_cast_kernel<<<F1, 64, 0, stream>>>(W1, wt1, F0, F1);
    transpose_cast_kernel<<<F2, 64, 0, stream>>>(W2, wt2, F1, F2);

    // layer 1
    {
        dim3 grid((N + 127) / 128, F1 / 128);
        gemm_mfma_kernel<128><<<grid, 256, 0, stream>>>(xb, wt1, h1, N, F0, F1);
    }
    agg_kernel<256, true, unsigned short><<<(N + 3) / 4, 256, 0, stream>>>(
        h1, dinv, offs, ssrc, wsrc, b1, h1a, N);

    // layer 2
    {
        dim3 grid((N + 127) / 128, F2 / 64);
        gemm_mfma_kernel<64><<<grid, 256, 0, stream>>>(h1a, wt2, h2, N, F1, F2);
    }
    agg_kernel<128, false, float><<<(N + 3) / 4, 256, 0, stream>>>(
        h2, dinv, offs, ssrc, wsrc, b2, out, N);
}

// Round 7
// 470.501 us; speedup vs baseline: 1.8866x; 1.1337x over previous
//
#include <hip/hip_runtime.h>
#include <hip/hip_bf16.h>

// N=50000, E=1600000, F0=256, F1=256, F2=128
// R6: agg1 pinned at ~107us / 3.7TB/s L2-miss path (MLP + wsrc neutral) ->
// declared plateau. R7: kill the serial single-block scan (suspected ~50-200us
// at 1-CU occupancy) with a 3-phase hierarchical scan; fuse dinv+cursor into
// the finalize phase; merge the two weight-transpose launches.

typedef __bf16 bf16x8 __attribute__((ext_vector_type(8)));
typedef float f32x4 __attribute__((ext_vector_type(4)));

__device__ inline unsigned short f2bf(float f) {
    unsigned u = __float_as_uint(f);
    u += 0x7FFFu + ((u >> 16) & 1u);  // RNE
    return (unsigned short)(u >> 16);
}
__device__ inline float bf16lo(unsigned q) { return __uint_as_float(q << 16); }
__device__ inline float bf16hi(unsigned q) { return __uint_as_float(q & 0xFFFF0000u); }
__device__ inline void storev(float* p, float v) { *p = v; }
__device__ inline void storev(unsigned short* p, float v) { *p = f2bf(v); }

// ---------------- CSR build (XCD-partitioned count/place from R3/R6) ----------------

#define XCDS 8

__global__ __launch_bounds__(256) void count_kernel_x(const int* __restrict__ dst,
                                                      int* __restrict__ cnt, int E, int ng) {
    int g = blockIdx.x & (XCDS - 1);
    int lo = g * ng, hi = lo + ng;
    int bid = blockIdx.x >> 3;
    int stride = (gridDim.x >> 3) * 256;
    for (int e = bid * 256 + threadIdx.x; e < E; e += stride) {
        int d = dst[e];
        if (d >= lo && d < hi) atomicAdd(&cnt[d], 1);
    }
}

__global__ __launch_bounds__(256) void place_kernel_x(const int* __restrict__ src,
                                                      const int* __restrict__ dst,
                                                      const float* __restrict__ dinv,
                                                      int* __restrict__ cursor,
                                                      int* __restrict__ ssrc,
                                                      float* __restrict__ wsrc, int E, int ng) {
    int g = blockIdx.x & (XCDS - 1);
    int lo = g * ng, hi = lo + ng;
    int bid = blockIdx.x >> 3;
    int stride = (gridDim.x >> 3) * 256;
    for (int e = bid * 256 + threadIdx.x; e < E; e += stride) {
        int d = dst[e];
        if (d >= lo && d < hi) {
            int s = src[e];
            int p = atomicAdd(&cursor[d], 1);
            ssrc[p] = s;
            wsrc[p] = dinv[s];
        }
    }
}

// ---------------- hierarchical scan: 1024 elems/block ----------------

__global__ __launch_bounds__(256) void scan_partial_kernel(const int* __restrict__ cnt,
                                                           int* __restrict__ bsum, int n) {
    __shared__ int s[256];
    int i0 = blockIdx.x * 1024 + threadIdx.x * 4;
    int lsum = 0;
#pragma unroll
    for (int j = 0; j < 4; ++j)
        if (i0 + j < n) lsum += cnt[i0 + j];
    s[threadIdx.x] = lsum;
    __syncthreads();
    for (int off = 128; off > 0; off >>= 1) {
        if (threadIdx.x < off) s[threadIdx.x] += s[threadIdx.x + off];
        __syncthreads();
    }
    if (threadIdx.x == 0) bsum[blockIdx.x] = s[0];
}

__global__ void scan_bsum_kernel(const int* __restrict__ bsum, int* __restrict__ bpre, int nb) {
    if (threadIdx.x == 0) {
        int r = 0;
        for (int b = 0; b < nb; ++b) { bpre[b] = r; r += bsum[b]; }
    }
}

// finalize: global exclusive prefix -> cursor, offs, dinv in one pass
__global__ __launch_bounds__(256) void scan_finalize_kernel(const int* __restrict__ cnt,
                                                            const int* __restrict__ bpre,
                                                            int* __restrict__ offs,
                                                            float* __restrict__ dinv,
                                                            int* __restrict__ cursor, int n) {
    __shared__ int s[256];
    int i0 = blockIdx.x * 1024 + threadIdx.x * 4;
    int v[4];
#pragma unroll
    for (int j = 0; j < 4; ++j) v[j] = (i0 + j < n) ? cnt[i0 + j] : 0;
    int lsum = v[0] + v[1] + v[2] + v[3];
    s[threadIdx.x] = lsum;
    __syncthreads();
    for (int off = 1; off < 256; off <<= 1) {
        int t = (threadIdx.x >= off) ? s[threadIdx.x - off] : 0;
        __syncthreads();
        s[threadIdx.x] += t;
        __syncthreads();
    }
    int run = s[threadIdx.x] - lsum + bpre[blockIdx.x];  // global exclusive prefix at i0
    if (blockIdx.x == 0 && threadIdx.x == 0) offs[0] = 0;
#pragma unroll
    for (int j = 0; j < 4; ++j) {
        int i = i0 + j;
        if (i < n) {
            cursor[i] = run;
            dinv[i] = rsqrtf((float)(v[j] + 1));
            run += v[j];
            offs[i + 1] = run;
        }
    }
}

// ---------------- casts ----------------

__global__ __launch_bounds__(256) void cast_bf16_kernel(const float* __restrict__ in,
                                                        unsigned short* __restrict__ out, int n) {
    int i = (blockIdx.x * 256 + threadIdx.x) * 8;
    if (i >= n) return;
    float4 a = *(const float4*)&in[i];
    float4 b = *(const float4*)&in[i + 4];
    uint4 p;
    p.x = (unsigned)f2bf(a.x) | ((unsigned)f2bf(a.y) << 16);
    p.y = (unsigned)f2bf(a.z) | ((unsigned)f2bf(a.w) << 16);
    p.z = (unsigned)f2bf(b.x) | ((unsigned)f2bf(b.y) << 16);
    p.w = (unsigned)f2bf(b.z) | ((unsigned)f2bf(b.w) << 16);
    *(uint4*)&out[i] = p;
}

// both weight transposes in one launch: blocks 0..255 -> W1, 256..383 -> W2
__global__ void transpose_cast2_kernel(const float* __restrict__ W1,
                                       unsigned short* __restrict__ Wt1,
                                       const float* __restrict__ W2,
                                       unsigned short* __restrict__ Wt2) {
    int b = blockIdx.x;
    if (b < 256) {
        for (int k = threadIdx.x; k < 256; k += 64)
            Wt1[(size_t)b * 256 + k] = f2bf(W1[(size_t)k * 256 + b]);
    } else {
        int n = b - 256;
        for (int k = threadIdx.x; k < 256; k += 64)
            Wt2[(size_t)n * 256 + k] = f2bf(W2[(size_t)k * 128 + n]);
    }
}

// ---------------- bf16 MFMA GEMM: C[M,N] = A @ Bt^T, bf16 out ----------------

template <int BN>
__global__ __launch_bounds__(256) void gemm_mfma_kernel(const unsigned short* __restrict__ A,
                                                        const unsigned short* __restrict__ Bt,
                                                        unsigned short* __restrict__ C,
                                                        int M, int K, int N) {
    constexpr int BM = 128, BK = 32, LDA = BK + 8;
    constexpr int CT = BN / 16;
    __shared__ unsigned short As[BM][LDA];
    __shared__ unsigned short Bs[BN][LDA];
    int tid = threadIdx.x;
    int wave = tid >> 6, lane = tid & 63;
    int quad = lane >> 4, l16 = lane & 15;
    int row0 = blockIdx.x * BM, col0 = blockIdx.y * BN;

    f32x4 acc[2][CT];
#pragma unroll
    for (int i = 0; i < 2; ++i)
#pragma unroll
        for (int j = 0; j < CT; ++j) acc[i][j] = (f32x4){0.f, 0.f, 0.f, 0.f};

    int ar = tid >> 2;
    int ac = (tid & 3) * 8;

    for (int k0 = 0; k0 < K; k0 += BK) {
#pragma unroll
        for (int i = 0; i < 2; ++i) {
            int r = ar + i * 64;
            int gr = row0 + r;
            uint4 v = make_uint4(0u, 0u, 0u, 0u);
            if (gr < M) v = *(const uint4*)&A[(size_t)gr * K + k0 + ac];
            *(uint4*)&As[r][ac] = v;
        }
#pragma unroll
        for (int i = 0; i < BN / 64; ++i) {
            int r = ar + i * 64;
            *(uint4*)&Bs[r][ac] = *(const uint4*)&Bt[(size_t)(col0 + r) * K + k0 + ac];
        }
        __syncthreads();
        bf16x8 af[2];
#pragma unroll
        for (int tr = 0; tr < 2; ++tr)
            af[tr] = *(const bf16x8*)&As[wave * 32 + tr * 16 + l16][quad * 8];
#pragma unroll
        for (int tc = 0; tc < CT; ++tc) {
            bf16x8 bf = *(const bf16x8*)&Bs[tc * 16 + l16][quad * 8];
            acc[0][tc] = __builtin_amdgcn_mfma_f32_16x16x32_bf16(af[0], bf, acc[0][tc], 0, 0, 0);
            acc[1][tc] = __builtin_amdgcn_mfma_f32_16x16x32_bf16(af[1], bf, acc[1][tc], 0, 0, 0);
        }
        __syncthreads();
    }
#pragma unroll
    for (int tr = 0; tr < 2; ++tr) {
        int gr0 = row0 + wave * 32 + tr * 16 + quad * 4;
#pragma unroll
        for (int tc = 0; tc < CT; ++tc) {
            int gc = col0 + tc * 16 + l16;
#pragma unroll
            for (int j = 0; j < 4; ++j) {
                int gr = gr0 + j;
                if (gr < M) C[(size_t)gr * N + gc] = f2bf(acc[tr][tc][j]);
            }
        }
    }
}

// ---------------- aggregation (R6): one wave per node, 8-edge unroll ----------------

template <int F, bool RELU, typename OT>
__global__ __launch_bounds__(256) void agg_kernel(const unsigned short* __restrict__ h,
                                                  const float* __restrict__ dinv,
                                                  const int* __restrict__ offs,
                                                  const int* __restrict__ ssrc,
                                                  const float* __restrict__ wsrc,
                                                  const float* __restrict__ bias,
                                                  OT* __restrict__ out, int N) {
    constexpr int V = F / 64;
    int n = blockIdx.x * 4 + (threadIdx.x >> 6);
    if (n >= N) return;
    int lane = threadIdx.x & 63;
    int c = lane * V;
    float di = dinv[n];
    float acc[V];

    {
        const unsigned short* p = h + (size_t)n * F + c;
        if constexpr (V == 4) {
            uint2 q = *(const uint2*)p;
            acc[0] = di * bf16lo(q.x); acc[1] = di * bf16hi(q.x);
            acc[2] = di * bf16lo(q.y); acc[3] = di * bf16hi(q.y);
        } else {
            unsigned q = *(const unsigned*)p;
            acc[0] = di * bf16lo(q); acc[1] = di * bf16hi(q);
        }
    }

    int e = offs[n], e1 = offs[n + 1];
    for (; e + 8 <= e1; e += 8) {
        int   s[8];
        float w[8];
#pragma unroll
        for (int j = 0; j < 8; ++j) s[j] = ssrc[e + j];
#pragma unroll
        for (int j = 0; j < 8; ++j) w[j] = wsrc[e + j];
        if constexpr (V == 4) {
            uint2 q[8];
#pragma unroll
            for (int j = 0; j < 8; ++j) q[j] = *(const uint2*)&h[(size_t)s[j] * F + c];
#pragma unroll
            for (int j = 0; j < 8; ++j) {
                acc[0] = fmaf(w[j], bf16lo(q[j].x), acc[0]);
                acc[1] = fmaf(w[j], bf16hi(q[j].x), acc[1]);
                acc[2] = fmaf(w[j], bf16lo(q[j].y), acc[2]);
                acc[3] = fmaf(w[j], bf16hi(q[j].y), acc[3]);
            }
        } else {
            unsigned q[8];
#pragma unroll
            for (int j = 0; j < 8; ++j) q[j] = *(const unsigned*)&h[(size_t)s[j] * F + c];
#pragma unroll
            for (int j = 0; j < 8; ++j) {
                acc[0] = fmaf(w[j], bf16lo(q[j]), acc[0]);
                acc[1] = fmaf(w[j], bf16hi(q[j]), acc[1]);
            }
        }
    }
    for (; e < e1; ++e) {
        int s = ssrc[e];
        float w = wsrc[e];
        const unsigned short* p = h + (size_t)s * F + c;
        if constexpr (V == 4) {
            uint2 q = *(const uint2*)p;
            acc[0] = fmaf(w, bf16lo(q.x), acc[0]);
            acc[1] = fmaf(w, bf16hi(q.x), acc[1]);
            acc[2] = fmaf(w, bf16lo(q.y), acc[2]);
            acc[3] = fmaf(w, bf16hi(q.y), acc[3]);
        } else {
            unsigned q = *(const unsigned*)p;
            acc[0] = fmaf(w, bf16lo(q), acc[0]);
            acc[1] = fmaf(w, bf16hi(q), acc[1]);
        }
    }

#pragma unroll
    for (int v = 0; v < V; ++v) {
        float r = fmaf(acc[v], di, bias[c + v]);
        if (RELU) r = fmaxf(r, 0.f);
        storev(&out[(size_t)n * F + c + v], r);
    }
}

// ---------------- launch ----------------

extern "C" void kernel_launch(void* const* d_in, const int* in_sizes, int n_in,
                              void* d_out, int out_size, void* d_ws, size_t ws_size,
                              hipStream_t stream) {
    const float* x  = (const float*)d_in[0];
    const int*   ei = (const int*)d_in[1];
    const float* W1 = (const float*)d_in[2];
    const float* b1 = (const float*)d_in[3];
    const float* W2 = (const float*)d_in[4];
    const float* b2 = (const float*)d_in[5];
    float* out = (float*)d_out;

    const int F0 = 256, F1 = 256, F2 = 128;
    const int N = in_sizes[0] / F0;   // 50000
    const int E = in_sizes[1] / 2;    // 1600000
    const int* src = ei;
    const int* dst = ei + E;
    const int ng = (N + XCDS - 1) / XCDS;
    const int NB = (N + 1023) / 1024;  // 49 scan blocks

    char* ws = (char*)d_ws;
    size_t off = 0;
    auto alloc = [&](size_t bytes) {
        char* p = ws + off;
        off += (bytes + 255) & ~(size_t)255;
        return p;
    };
    int*            cnt    = (int*)alloc((size_t)N * 4);
    int*            offs   = (int*)alloc((size_t)(N + 1) * 4);
    int*            cursor = (int*)alloc((size_t)N * 4);
    float*          dinv   = (float*)alloc((size_t)N * 4);
    int*            bsum   = (int*)alloc((size_t)NB * 4);
    int*            bpre   = (int*)alloc((size_t)NB * 4);
    int*            ssrc   = (int*)alloc((size_t)E * 4);
    float*          wsrc   = (float*)alloc((size_t)E * 4);
    unsigned short* xb     = (unsigned short*)alloc((size_t)N * F0 * 2);
    unsigned short* wt1    = (unsigned short*)alloc((size_t)F1 * F0 * 2);
    unsigned short* wt2    = (unsigned short*)alloc((size_t)F2 * F1 * 2);
    unsigned short* h1     = (unsigned short*)alloc((size_t)N * F1 * 2);
    unsigned short* h1a    = (unsigned short*)alloc((size_t)N * F1 * 2);
    unsigned short* h2     = (unsigned short*)alloc((size_t)N * F2 * 2);
    (void)ws_size; (void)n_in; (void)out_size;

    // CSR build
    hipMemsetAsync(cnt, 0, (size_t)N * 4, stream);
    count_kernel_x<<<2048, 256, 0, stream>>>(dst, cnt, E, ng);
    scan_partial_kernel<<<NB, 256, 0, stream>>>(cnt, bsum, N);
    scan_bsum_kernel<<<1, 64, 0, stream>>>(bsum, bpre, NB);
    scan_finalize_kernel<<<NB, 256, 0, stream>>>(cnt, bpre, offs, dinv, cursor, N);
    place_kernel_x<<<2048, 256, 0, stream>>>(src, dst, dinv, cursor, ssrc, wsrc, E, ng);

    // casts
    cast_bf16_kernel<<<(N * F0) / 2048, 256, 0, stream>>>(x, xb, N * F0);
    transpose_cast2_kernel<<<384, 64, 0, stream>>>(W1, wt1, W2, wt2);

    // layer 1
    {
        dim3 grid((N + 127) / 128, F1 / 128);
        gemm_mfma_kernel<128><<<grid, 256, 0, stream>>>(xb, wt1, h1, N, F0, F1);
    }
    agg_kernel<256, true, unsigned short><<<(N + 3) / 4, 256, 0, stream>>>(
        h1, dinv, offs, ssrc, wsrc, b1, h1a, N);

    // layer 2
    {
        dim3 grid((N + 127) / 128, F2 / 64);
        gemm_mfma_kernel<64><<<grid, 256, 0, stream>>>(h1a, wt2, h2, N, F1, F2);
    }
    agg_kernel<128, false, float><<<(N + 3) / 4, 256, 0, stream>>>(
        h2, dinv, offs, ssrc, wsrc, b2, out, N);
}

// Round 8
// 462.721 us; speedup vs baseline: 1.9183x; 1.0168x over previous
//
#include <hip/hip_runtime.h>
#include <hip/hip_bf16.h>

// N=50000, E=1600000, F0=256, F1=256, F2=128
// R7 killed the serial scan (-63us). R8 shavings:
//  - cast_bf16 fused into gemm1 A-staging (fp32->bf16 in-register; -77MB, -1 launch)
//  - scan_bsum fused into scan_finalize (-1 launch)
//  - count reverted to single-sweep: atomics never had the partial-line
//    write-amplification that motivated the 8x XCD sweep (that was for plain
//    stores in place); single sweep reads 6.4MB not 51MB.

typedef __bf16 bf16x8 __attribute__((ext_vector_type(8)));
typedef float f32x4 __attribute__((ext_vector_type(4)));

__device__ inline unsigned short f2bf(float f) {
    unsigned u = __float_as_uint(f);
    u += 0x7FFFu + ((u >> 16) & 1u);  // RNE
    return (unsigned short)(u >> 16);
}
__device__ inline float bf16lo(unsigned q) { return __uint_as_float(q << 16); }
__device__ inline float bf16hi(unsigned q) { return __uint_as_float(q & 0xFFFF0000u); }
__device__ inline void storev(float* p, float v) { *p = v; }
__device__ inline void storev(unsigned short* p, float v) { *p = f2bf(v); }

#define XCDS 8

// ---------------- CSR build ----------------

// single sweep, plain device atomics (no line amplification for atomics)
__global__ __launch_bounds__(256) void count_kernel(const int* __restrict__ dst,
                                                    int* __restrict__ cnt, int E) {
    int e = blockIdx.x * 256 + threadIdx.x;
    if (e < E) atomicAdd(&cnt[dst[e]], 1);
}

// XCD-partitioned placement (plain stores DO amplify across XCDs -> keep)
__global__ __launch_bounds__(256) void place_kernel_x(const int* __restrict__ src,
                                                      const int* __restrict__ dst,
                                                      const float* __restrict__ dinv,
                                                      int* __restrict__ cursor,
                                                      int* __restrict__ ssrc,
                                                      float* __restrict__ wsrc, int E, int ng) {
    int g = blockIdx.x & (XCDS - 1);
    int lo = g * ng, hi = lo + ng;
    int bid = blockIdx.x >> 3;
    int stride = (gridDim.x >> 3) * 256;
    for (int e = bid * 256 + threadIdx.x; e < E; e += stride) {
        int d = dst[e];
        if (d >= lo && d < hi) {
            int s = src[e];
            int p = atomicAdd(&cursor[d], 1);
            ssrc[p] = s;
            wsrc[p] = dinv[s];
        }
    }
}

// ---------------- hierarchical scan (2 kernels) ----------------

__global__ __launch_bounds__(256) void scan_partial_kernel(const int* __restrict__ cnt,
                                                           int* __restrict__ bsum, int n) {
    __shared__ int s[256];
    int i0 = blockIdx.x * 1024 + threadIdx.x * 4;
    int lsum = 0;
#pragma unroll
    for (int j = 0; j < 4; ++j)
        if (i0 + j < n) lsum += cnt[i0 + j];
    s[threadIdx.x] = lsum;
    __syncthreads();
    for (int off = 128; off > 0; off >>= 1) {
        if (threadIdx.x < off) s[threadIdx.x] += s[threadIdx.x + off];
        __syncthreads();
    }
    if (threadIdx.x == 0) bsum[blockIdx.x] = s[0];
}

// finalize: computes its own bsum-prefix (nb<=64 values), then
// global exclusive prefix -> cursor, offs, dinv in one pass
__global__ __launch_bounds__(256) void scan_finalize_kernel(const int* __restrict__ cnt,
                                                            const int* __restrict__ bsum,
                                                            int* __restrict__ offs,
                                                            float* __restrict__ dinv,
                                                            int* __restrict__ cursor,
                                                            int n, int nb) {
    __shared__ int s[256];
    __shared__ int bpre_s;
    if (threadIdx.x == 0) {
        int r = 0;
        for (int b = 0; b < (int)blockIdx.x; ++b) r += bsum[b];
        bpre_s = r;
    }
    int i0 = blockIdx.x * 1024 + threadIdx.x * 4;
    int v[4];
#pragma unroll
    for (int j = 0; j < 4; ++j) v[j] = (i0 + j < n) ? cnt[i0 + j] : 0;
    int lsum = v[0] + v[1] + v[2] + v[3];
    s[threadIdx.x] = lsum;
    __syncthreads();
    for (int off = 1; off < 256; off <<= 1) {
        int t = (threadIdx.x >= off) ? s[threadIdx.x - off] : 0;
        __syncthreads();
        s[threadIdx.x] += t;
        __syncthreads();
    }
    int run = s[threadIdx.x] - lsum + bpre_s;
    if (blockIdx.x == 0 && threadIdx.x == 0) offs[0] = 0;
#pragma unroll
    for (int j = 0; j < 4; ++j) {
        int i = i0 + j;
        if (i < n) {
            cursor[i] = run;
            dinv[i] = rsqrtf((float)(v[j] + 1));
            run += v[j];
            offs[i + 1] = run;
        }
    }
}

// ---------------- weight transpose+cast ----------------

__global__ void transpose_cast2_kernel(const float* __restrict__ W1,
                                       unsigned short* __restrict__ Wt1,
                                       const float* __restrict__ W2,
                                       unsigned short* __restrict__ Wt2) {
    int b = blockIdx.x;
    if (b < 256) {
        for (int k = threadIdx.x; k < 256; k += 64)
            Wt1[(size_t)b * 256 + k] = f2bf(W1[(size_t)k * 256 + b]);
    } else {
        int n = b - 256;
        for (int k = threadIdx.x; k < 256; k += 64)
            Wt2[(size_t)n * 256 + k] = f2bf(W2[(size_t)k * 128 + n]);
    }
}

// ---------------- bf16 MFMA GEMM ----------------
// AFP32: A is fp32, converted to bf16 in-register during staging (layer 1).
// Otherwise A is bf16. Bt is bf16 [N][K]. C out bf16.

template <int BN, bool AFP32>
__global__ __launch_bounds__(256) void gemm_mfma_kernel(const void* __restrict__ Av,
                                                        const unsigned short* __restrict__ Bt,
                                                        unsigned short* __restrict__ C,
                                                        int M, int K, int N) {
    constexpr int BM = 128, BK = 32, LDA = BK + 8;
    constexpr int CT = BN / 16;
    __shared__ unsigned short As[BM][LDA];
    __shared__ unsigned short Bs[BN][LDA];
    int tid = threadIdx.x;
    int wave = tid >> 6, lane = tid & 63;
    int quad = lane >> 4, l16 = lane & 15;
    int row0 = blockIdx.x * BM, col0 = blockIdx.y * BN;

    f32x4 acc[2][CT];
#pragma unroll
    for (int i = 0; i < 2; ++i)
#pragma unroll
        for (int j = 0; j < CT; ++j) acc[i][j] = (f32x4){0.f, 0.f, 0.f, 0.f};

    int ar = tid >> 2;
    int ac = (tid & 3) * 8;

    for (int k0 = 0; k0 < K; k0 += BK) {
#pragma unroll
        for (int i = 0; i < 2; ++i) {
            int r = ar + i * 64;
            int gr = row0 + r;
            uint4 v = make_uint4(0u, 0u, 0u, 0u);
            if (gr < M) {
                if constexpr (AFP32) {
                    const float* A = (const float*)Av;
                    float4 a = *(const float4*)&A[(size_t)gr * K + k0 + ac];
                    float4 b = *(const float4*)&A[(size_t)gr * K + k0 + ac + 4];
                    v.x = (unsigned)f2bf(a.x) | ((unsigned)f2bf(a.y) << 16);
                    v.y = (unsigned)f2bf(a.z) | ((unsigned)f2bf(a.w) << 16);
                    v.z = (unsigned)f2bf(b.x) | ((unsigned)f2bf(b.y) << 16);
                    v.w = (unsigned)f2bf(b.z) | ((unsigned)f2bf(b.w) << 16);
                } else {
                    const unsigned short* A = (const unsigned short*)Av;
                    v = *(const uint4*)&A[(size_t)gr * K + k0 + ac];
                }
            }
            *(uint4*)&As[r][ac] = v;
        }
#pragma unroll
        for (int i = 0; i < BN / 64; ++i) {
            int r = ar + i * 64;
            *(uint4*)&Bs[r][ac] = *(const uint4*)&Bt[(size_t)(col0 + r) * K + k0 + ac];
        }
        __syncthreads();
        bf16x8 af[2];
#pragma unroll
        for (int tr = 0; tr < 2; ++tr)
            af[tr] = *(const bf16x8*)&As[wave * 32 + tr * 16 + l16][quad * 8];
#pragma unroll
        for (int tc = 0; tc < CT; ++tc) {
            bf16x8 bf = *(const bf16x8*)&Bs[tc * 16 + l16][quad * 8];
            acc[0][tc] = __builtin_amdgcn_mfma_f32_16x16x32_bf16(af[0], bf, acc[0][tc], 0, 0, 0);
            acc[1][tc] = __builtin_amdgcn_mfma_f32_16x16x32_bf16(af[1], bf, acc[1][tc], 0, 0, 0);
        }
        __syncthreads();
    }
#pragma unroll
    for (int tr = 0; tr < 2; ++tr) {
        int gr0 = row0 + wave * 32 + tr * 16 + quad * 4;
#pragma unroll
        for (int tc = 0; tc < CT; ++tc) {
            int gc = col0 + tc * 16 + l16;
#pragma unroll
            for (int j = 0; j < 4; ++j) {
                int gr = gr0 + j;
                if (gr < M) C[(size_t)gr * N + gc] = f2bf(acc[tr][tc][j]);
            }
        }
    }
}

// ---------------- aggregation (R6): one wave per node, 8-edge unroll ----------------

template <int F, bool RELU, typename OT>
__global__ __launch_bounds__(256) void agg_kernel(const unsigned short* __restrict__ h,
                                                  const float* __restrict__ dinv,
                                                  const int* __restrict__ offs,
                                                  const int* __restrict__ ssrc,
                                                  const float* __restrict__ wsrc,
                                                  const float* __restrict__ bias,
                                                  OT* __restrict__ out, int N) {
    constexpr int V = F / 64;
    int n = blockIdx.x * 4 + (threadIdx.x >> 6);
    if (n >= N) return;
    int lane = threadIdx.x & 63;
    int c = lane * V;
    float di = dinv[n];
    float acc[V];

    {
        const unsigned short* p = h + (size_t)n * F + c;
        if constexpr (V == 4) {
            uint2 q = *(const uint2*)p;
            acc[0] = di * bf16lo(q.x); acc[1] = di * bf16hi(q.x);
            acc[2] = di * bf16lo(q.y); acc[3] = di * bf16hi(q.y);
        } else {
            unsigned q = *(const unsigned*)p;
            acc[0] = di * bf16lo(q); acc[1] = di * bf16hi(q);
        }
    }

    int e = offs[n], e1 = offs[n + 1];
    for (; e + 8 <= e1; e += 8) {
        int   s[8];
        float w[8];
#pragma unroll
        for (int j = 0; j < 8; ++j) s[j] = ssrc[e + j];
#pragma unroll
        for (int j = 0; j < 8; ++j) w[j] = wsrc[e + j];
        if constexpr (V == 4) {
            uint2 q[8];
#pragma unroll
            for (int j = 0; j < 8; ++j) q[j] = *(const uint2*)&h[(size_t)s[j] * F + c];
#pragma unroll
            for (int j = 0; j < 8; ++j) {
                acc[0] = fmaf(w[j], bf16lo(q[j].x), acc[0]);
                acc[1] = fmaf(w[j], bf16hi(q[j].x), acc[1]);
                acc[2] = fmaf(w[j], bf16lo(q[j].y), acc[2]);
                acc[3] = fmaf(w[j], bf16hi(q[j].y), acc[3]);
            }
        } else {
            unsigned q[8];
#pragma unroll
            for (int j = 0; j < 8; ++j) q[j] = *(const unsigned*)&h[(size_t)s[j] * F + c];
#pragma unroll
            for (int j = 0; j < 8; ++j) {
                acc[0] = fmaf(w[j], bf16lo(q[j]), acc[0]);
                acc[1] = fmaf(w[j], bf16hi(q[j]), acc[1]);
            }
        }
    }
    for (; e < e1; ++e) {
        int s = ssrc[e];
        float w = wsrc[e];
        const unsigned short* p = h + (size_t)s * F + c;
        if constexpr (V == 4) {
            uint2 q = *(const uint2*)p;
            acc[0] = fmaf(w, bf16lo(q.x), acc[0]);
            acc[1] = fmaf(w, bf16hi(q.x), acc[1]);
            acc[2] = fmaf(w, bf16lo(q.y), acc[2]);
            acc[3] = fmaf(w, bf16hi(q.y), acc[3]);
        } else {
            unsigned q = *(const unsigned*)p;
            acc[0] = fmaf(w, bf16lo(q), acc[0]);
            acc[1] = fmaf(w, bf16hi(q), acc[1]);
        }
    }

#pragma unroll
    for (int v = 0; v < V; ++v) {
        float r = fmaf(acc[v], di, bias[c + v]);
        if (RELU) r = fmaxf(r, 0.f);
        storev(&out[(size_t)n * F + c + v], r);
    }
}

// ---------------- launch ----------------

extern "C" void kernel_launch(void* const* d_in, const int* in_sizes, int n_in,
                              void* d_out, int out_size, void* d_ws, size_t ws_size,
                              hipStream_t stream) {
    const float* x  = (const float*)d_in[0];
    const int*   ei = (const int*)d_in[1];
    const float* W1 = (const float*)d_in[2];
    const float* b1 = (const float*)d_in[3];
    const float* W2 = (const float*)d_in[4];
    const float* b2 = (const float*)d_in[5];
    float* out = (float*)d_out;

    const int F0 = 256, F1 = 256, F2 = 128;
    const int N = in_sizes[0] / F0;   // 50000
    const int E = in_sizes[1] / 2;    // 1600000
    const int* src = ei;
    const int* dst = ei + E;
    const int ng = (N + XCDS - 1) / XCDS;
    const int NB = (N + 1023) / 1024;  // 49 scan blocks

    char* ws = (char*)d_ws;
    size_t off = 0;
    auto alloc = [&](size_t bytes) {
        char* p = ws + off;
        off += (bytes + 255) & ~(size_t)255;
        return p;
    };
    int*            cnt    = (int*)alloc((size_t)N * 4);
    int*            offs   = (int*)alloc((size_t)(N + 1) * 4);
    int*            cursor = (int*)alloc((size_t)N * 4);
    float*          dinv   = (float*)alloc((size_t)N * 4);
    int*            bsum   = (int*)alloc((size_t)NB * 4);
    int*            ssrc   = (int*)alloc((size_t)E * 4);
    float*          wsrc   = (float*)alloc((size_t)E * 4);
    unsigned short* wt1    = (unsigned short*)alloc((size_t)F1 * F0 * 2);
    unsigned short* wt2    = (unsigned short*)alloc((size_t)F2 * F1 * 2);
    unsigned short* h1     = (unsigned short*)alloc((size_t)N * F1 * 2);
    unsigned short* h1a    = (unsigned short*)alloc((size_t)N * F1 * 2);
    unsigned short* h2     = (unsigned short*)alloc((size_t)N * F2 * 2);
    (void)ws_size; (void)n_in; (void)out_size;

    // CSR build
    hipMemsetAsync(cnt, 0, (size_t)N * 4, stream);
    count_kernel<<<(E + 255) / 256, 256, 0, stream>>>(dst, cnt, E);
    scan_partial_kernel<<<NB, 256, 0, stream>>>(cnt, bsum, N);
    scan_finalize_kernel<<<NB, 256, 0, stream>>>(cnt, bsum, offs, dinv, cursor, N, NB);
    place_kernel_x<<<2048, 256, 0, stream>>>(src, dst, dinv, cursor, ssrc, wsrc, E, ng);

    // weights
    transpose_cast2_kernel<<<384, 64, 0, stream>>>(W1, wt1, W2, wt2);

    // layer 1: gemm reads fp32 x directly (in-register cast)
    {
        dim3 grid((N + 127) / 128, F1 / 128);
        gemm_mfma_kernel<128, true><<<grid, 256, 0, stream>>>(x, wt1, h1, N, F0, F1);
    }
    agg_kernel<256, true, unsigned short><<<(N + 3) / 4, 256, 0, stream>>>(
        h1, dinv, offs, ssrc, wsrc, b1, h1a, N);

    // layer 2
    {
        dim3 grid((N + 127) / 128, F2 / 64);
        gemm_mfma_kernel<64, false><<<grid, 256, 0, stream>>>(h1a, wt2, h2, N, F1, F2);
    }
    agg_kernel<128, false, float><<<(N + 3) / 4, 256, 0, stream>>>(
        h2, dinv, offs, ssrc, wsrc, b2, out, N);
}

// Round 9
// 415.035 us; speedup vs baseline: 2.1387x; 1.1149x over previous
//
#include <hip/hip_runtime.h>
#include <hip/hip_bf16.h>

// N=50000, E=1600000, F0=256, F1=256, F2=128
// R8 post-mortem: count single-sweep revert was a regression (untested theory);
// agg1 pinned at 3.65TB/s random-line service rate across 4 rounds -> only
// lever left is BYTES. R9:
//  - h1 stored fp8-e4m3 (encode in gemm1 epilogue, HW cvt decode in agg1):
//    gather rows 512->256B, working set 25.6->12.8MB
//  - count_kernel_x restored (R7 measured config)

typedef __bf16 bf16x8 __attribute__((ext_vector_type(8)));
typedef float f32x4 __attribute__((ext_vector_type(4)));
typedef float f32x2 __attribute__((ext_vector_type(2)));

__device__ inline unsigned short f2bf(float f) {
    unsigned u = __float_as_uint(f);
    u += 0x7FFFu + ((u >> 16) & 1u);  // RNE
    return (unsigned short)(u >> 16);
}
__device__ inline float bf16lo(unsigned q) { return __uint_as_float(q << 16); }
__device__ inline float bf16hi(unsigned q) { return __uint_as_float(q & 0xFFFF0000u); }
__device__ inline void storev(float* p, float v) { *p = v; }
__device__ inline void storev(unsigned short* p, float v) { *p = f2bf(v); }

#define XCDS 8

// ---------------- CSR build (XCD-partitioned, R7 config) ----------------

__global__ __launch_bounds__(256) void count_kernel_x(const int* __restrict__ dst,
                                                      int* __restrict__ cnt, int E, int ng) {
    int g = blockIdx.x & (XCDS - 1);
    int lo = g * ng, hi = lo + ng;
    int bid = blockIdx.x >> 3;
    int stride = (gridDim.x >> 3) * 256;
    for (int e = bid * 256 + threadIdx.x; e < E; e += stride) {
        int d = dst[e];
        if (d >= lo && d < hi) atomicAdd(&cnt[d], 1);
    }
}

__global__ __launch_bounds__(256) void place_kernel_x(const int* __restrict__ src,
                                                      const int* __restrict__ dst,
                                                      const float* __restrict__ dinv,
                                                      int* __restrict__ cursor,
                                                      int* __restrict__ ssrc,
                                                      float* __restrict__ wsrc, int E, int ng) {
    int g = blockIdx.x & (XCDS - 1);
    int lo = g * ng, hi = lo + ng;
    int bid = blockIdx.x >> 3;
    int stride = (gridDim.x >> 3) * 256;
    for (int e = bid * 256 + threadIdx.x; e < E; e += stride) {
        int d = dst[e];
        if (d >= lo && d < hi) {
            int s = src[e];
            int p = atomicAdd(&cursor[d], 1);
            ssrc[p] = s;
            wsrc[p] = dinv[s];
        }
    }
}

// ---------------- hierarchical scan ----------------

__global__ __launch_bounds__(256) void scan_partial_kernel(const int* __restrict__ cnt,
                                                           int* __restrict__ bsum, int n) {
    __shared__ int s[256];
    int i0 = blockIdx.x * 1024 + threadIdx.x * 4;
    int lsum = 0;
#pragma unroll
    for (int j = 0; j < 4; ++j)
        if (i0 + j < n) lsum += cnt[i0 + j];
    s[threadIdx.x] = lsum;
    __syncthreads();
    for (int off = 128; off > 0; off >>= 1) {
        if (threadIdx.x < off) s[threadIdx.x] += s[threadIdx.x + off];
        __syncthreads();
    }
    if (threadIdx.x == 0) bsum[blockIdx.x] = s[0];
}

__global__ __launch_bounds__(256) void scan_finalize_kernel(const int* __restrict__ cnt,
                                                            const int* __restrict__ bsum,
                                                            int* __restrict__ offs,
                                                            float* __restrict__ dinv,
                                                            int* __restrict__ cursor,
                                                            int n, int nb) {
    __shared__ int s[256];
    __shared__ int bpre_s;
    if (threadIdx.x == 0) {
        int r = 0;
        for (int b = 0; b < (int)blockIdx.x; ++b) r += bsum[b];
        bpre_s = r;
    }
    int i0 = blockIdx.x * 1024 + threadIdx.x * 4;
    int v[4];
#pragma unroll
    for (int j = 0; j < 4; ++j) v[j] = (i0 + j < n) ? cnt[i0 + j] : 0;
    int lsum = v[0] + v[1] + v[2] + v[3];
    s[threadIdx.x] = lsum;
    __syncthreads();
    for (int off = 1; off < 256; off <<= 1) {
        int t = (threadIdx.x >= off) ? s[threadIdx.x - off] : 0;
        __syncthreads();
        s[threadIdx.x] += t;
        __syncthreads();
    }
    int run = s[threadIdx.x] - lsum + bpre_s;
    if (blockIdx.x == 0 && threadIdx.x == 0) offs[0] = 0;
#pragma unroll
    for (int j = 0; j < 4; ++j) {
        int i = i0 + j;
        if (i < n) {
            cursor[i] = run;
            dinv[i] = rsqrtf((float)(v[j] + 1));
            run += v[j];
            offs[i + 1] = run;
        }
    }
}

// ---------------- weight transpose+cast ----------------

__global__ void transpose_cast2_kernel(const float* __restrict__ W1,
                                       unsigned short* __restrict__ Wt1,
                                       const float* __restrict__ W2,
                                       unsigned short* __restrict__ Wt2) {
    int b = blockIdx.x;
    if (b < 256) {
        for (int k = threadIdx.x; k < 256; k += 64)
            Wt1[(size_t)b * 256 + k] = f2bf(W1[(size_t)k * 256 + b]);
    } else {
        int n = b - 256;
        for (int k = threadIdx.x; k < 256; k += 64)
            Wt2[(size_t)n * 256 + k] = f2bf(W2[(size_t)k * 128 + n]);
    }
}

// ---------------- bf16 MFMA GEMM ----------------
// AFP32: A fp32, cast to bf16 in-register during staging. OUT8: C stored fp8-e4m3.

template <int BN, bool AFP32, bool OUT8>
__global__ __launch_bounds__(256) void gemm_mfma_kernel(const void* __restrict__ Av,
                                                        const unsigned short* __restrict__ Bt,
                                                        void* __restrict__ Cv,
                                                        int M, int K, int N) {
    constexpr int BM = 128, BK = 32, LDA = BK + 8;
    constexpr int CT = BN / 16;
    __shared__ unsigned short As[BM][LDA];
    __shared__ unsigned short Bs[BN][LDA];
    int tid = threadIdx.x;
    int wave = tid >> 6, lane = tid & 63;
    int quad = lane >> 4, l16 = lane & 15;
    int row0 = blockIdx.x * BM, col0 = blockIdx.y * BN;

    f32x4 acc[2][CT];
#pragma unroll
    for (int i = 0; i < 2; ++i)
#pragma unroll
        for (int j = 0; j < CT; ++j) acc[i][j] = (f32x4){0.f, 0.f, 0.f, 0.f};

    int ar = tid >> 2;
    int ac = (tid & 3) * 8;

    for (int k0 = 0; k0 < K; k0 += BK) {
#pragma unroll
        for (int i = 0; i < 2; ++i) {
            int r = ar + i * 64;
            int gr = row0 + r;
            uint4 v = make_uint4(0u, 0u, 0u, 0u);
            if (gr < M) {
                if constexpr (AFP32) {
                    const float* A = (const float*)Av;
                    float4 a = *(const float4*)&A[(size_t)gr * K + k0 + ac];
                    float4 b = *(const float4*)&A[(size_t)gr * K + k0 + ac + 4];
                    v.x = (unsigned)f2bf(a.x) | ((unsigned)f2bf(a.y) << 16);
                    v.y = (unsigned)f2bf(a.z) | ((unsigned)f2bf(a.w) << 16);
                    v.z = (unsigned)f2bf(b.x) | ((unsigned)f2bf(b.y) << 16);
                    v.w = (unsigned)f2bf(b.z) | ((unsigned)f2bf(b.w) << 16);
                } else {
                    const unsigned short* A = (const unsigned short*)Av;
                    v = *(const uint4*)&A[(size_t)gr * K + k0 + ac];
                }
            }
            *(uint4*)&As[r][ac] = v;
        }
#pragma unroll
        for (int i = 0; i < BN / 64; ++i) {
            int r = ar + i * 64;
            *(uint4*)&Bs[r][ac] = *(const uint4*)&Bt[(size_t)(col0 + r) * K + k0 + ac];
        }
        __syncthreads();
        bf16x8 af[2];
#pragma unroll
        for (int tr = 0; tr < 2; ++tr)
            af[tr] = *(const bf16x8*)&As[wave * 32 + tr * 16 + l16][quad * 8];
#pragma unroll
        for (int tc = 0; tc < CT; ++tc) {
            bf16x8 bf = *(const bf16x8*)&Bs[tc * 16 + l16][quad * 8];
            acc[0][tc] = __builtin_amdgcn_mfma_f32_16x16x32_bf16(af[0], bf, acc[0][tc], 0, 0, 0);
            acc[1][tc] = __builtin_amdgcn_mfma_f32_16x16x32_bf16(af[1], bf, acc[1][tc], 0, 0, 0);
        }
        __syncthreads();
    }
#pragma unroll
    for (int tr = 0; tr < 2; ++tr) {
        int gr0 = row0 + wave * 32 + tr * 16 + quad * 4;
#pragma unroll
        for (int tc = 0; tc < CT; ++tc) {
            int gc = col0 + tc * 16 + l16;
#pragma unroll
            for (int j = 0; j < 4; ++j) {
                int gr = gr0 + j;
                if (gr < M) {
                    if constexpr (OUT8) {
                        unsigned char* C = (unsigned char*)Cv;
                        int p = __builtin_amdgcn_cvt_pk_fp8_f32(acc[tr][tc][j], 0.f, 0, false);
                        C[(size_t)gr * N + gc] = (unsigned char)(p & 0xFF);
                    } else {
                        unsigned short* C = (unsigned short*)Cv;
                        C[(size_t)gr * N + gc] = f2bf(acc[tr][tc][j]);
                    }
                }
            }
        }
    }
}

// ---------------- agg1: fp8 gather (F=256), bf16 out, ReLU ----------------
// lane owns 4 cols = 1 uint of fp8; 64 lanes x 4B = 256B row, fully coalesced.

__global__ __launch_bounds__(256) void agg_fp8_kernel(const unsigned char* __restrict__ h,
                                                      const float* __restrict__ dinv,
                                                      const int* __restrict__ offs,
                                                      const int* __restrict__ ssrc,
                                                      const float* __restrict__ wsrc,
                                                      const float* __restrict__ bias,
                                                      unsigned short* __restrict__ out, int N) {
    constexpr int F = 256;
    int n = blockIdx.x * 4 + (threadIdx.x >> 6);
    if (n >= N) return;
    int lane = threadIdx.x & 63;
    int c = lane * 4;
    float di = dinv[n];
    float acc[4];

    auto dec_fma = [&](unsigned q, float w, float* a) {
        f32x2 lo = __builtin_amdgcn_cvt_pk_f32_fp8(q, false);
        f32x2 hi = __builtin_amdgcn_cvt_pk_f32_fp8(q, true);
        a[0] = fmaf(w, lo.x, a[0]);
        a[1] = fmaf(w, lo.y, a[1]);
        a[2] = fmaf(w, hi.x, a[2]);
        a[3] = fmaf(w, hi.y, a[3]);
    };

    {
        unsigned q = *(const unsigned*)&h[(size_t)n * F + c];
        f32x2 lo = __builtin_amdgcn_cvt_pk_f32_fp8(q, false);
        f32x2 hi = __builtin_amdgcn_cvt_pk_f32_fp8(q, true);
        acc[0] = di * lo.x; acc[1] = di * lo.y;
        acc[2] = di * hi.x; acc[3] = di * hi.y;
    }

    int e = offs[n], e1 = offs[n + 1];
    for (; e + 8 <= e1; e += 8) {
        int   s[8];
        float w[8];
        unsigned q[8];
#pragma unroll
        for (int j = 0; j < 8; ++j) s[j] = ssrc[e + j];
#pragma unroll
        for (int j = 0; j < 8; ++j) w[j] = wsrc[e + j];
#pragma unroll
        for (int j = 0; j < 8; ++j) q[j] = *(const unsigned*)&h[(size_t)s[j] * F + c];
#pragma unroll
        for (int j = 0; j < 8; ++j) dec_fma(q[j], w[j], acc);
    }
    for (; e < e1; ++e) {
        unsigned q = *(const unsigned*)&h[(size_t)ssrc[e] * F + c];
        dec_fma(q, wsrc[e], acc);
    }

#pragma unroll
    for (int v = 0; v < 4; ++v) {
        float r = fmaf(acc[v], di, bias[c + v]);
        acc[v] = fmaxf(r, 0.f);
    }
    uint2 p;
    p.x = (unsigned)f2bf(acc[0]) | ((unsigned)f2bf(acc[1]) << 16);
    p.y = (unsigned)f2bf(acc[2]) | ((unsigned)f2bf(acc[3]) << 16);
    *(uint2*)&out[(size_t)n * F + c] = p;
}

// ---------------- agg2: bf16 gather (F=128), fp32 out ----------------

__global__ __launch_bounds__(256) void agg_bf16_kernel(const unsigned short* __restrict__ h,
                                                       const float* __restrict__ dinv,
                                                       const int* __restrict__ offs,
                                                       const int* __restrict__ ssrc,
                                                       const float* __restrict__ wsrc,
                                                       const float* __restrict__ bias,
                                                       float* __restrict__ out, int N) {
    constexpr int F = 128;
    int n = blockIdx.x * 4 + (threadIdx.x >> 6);
    if (n >= N) return;
    int lane = threadIdx.x & 63;
    int c = lane * 2;
    float di = dinv[n];
    float a0, a1;
    {
        unsigned q = *(const unsigned*)&h[(size_t)n * F + c];
        a0 = di * bf16lo(q); a1 = di * bf16hi(q);
    }
    int e = offs[n], e1 = offs[n + 1];
    for (; e + 8 <= e1; e += 8) {
        int   s[8];
        float w[8];
        unsigned q[8];
#pragma unroll
        for (int j = 0; j < 8; ++j) s[j] = ssrc[e + j];
#pragma unroll
        for (int j = 0; j < 8; ++j) w[j] = wsrc[e + j];
#pragma unroll
        for (int j = 0; j < 8; ++j) q[j] = *(const unsigned*)&h[(size_t)s[j] * F + c];
#pragma unroll
        for (int j = 0; j < 8; ++j) {
            a0 = fmaf(w[j], bf16lo(q[j]), a0);
            a1 = fmaf(w[j], bf16hi(q[j]), a1);
        }
    }
    for (; e < e1; ++e) {
        unsigned q = *(const unsigned*)&h[(size_t)ssrc[e] * F + c];
        float w = wsrc[e];
        a0 = fmaf(w, bf16lo(q), a0);
        a1 = fmaf(w, bf16hi(q), a1);
    }
    float r0 = fmaf(a0, di, bias[c]);
    float r1 = fmaf(a1, di, bias[c + 1]);
    *(float2*)&out[(size_t)n * F + c] = make_float2(r0, r1);
}

// ---------------- launch ----------------

extern "C" void kernel_launch(void* const* d_in, const int* in_sizes, int n_in,
                              void* d_out, int out_size, void* d_ws, size_t ws_size,
                              hipStream_t stream) {
    const float* x  = (const float*)d_in[0];
    const int*   ei = (const int*)d_in[1];
    const float* W1 = (const float*)d_in[2];
    const float* b1 = (const float*)d_in[3];
    const float* W2 = (const float*)d_in[4];
    const float* b2 = (const float*)d_in[5];
    float* out = (float*)d_out;

    const int F0 = 256, F1 = 256, F2 = 128;
    const int N = in_sizes[0] / F0;   // 50000
    const int E = in_sizes[1] / 2;    // 1600000
    const int* src = ei;
    const int* dst = ei + E;
    const int ng = (N + XCDS - 1) / XCDS;
    const int NB = (N + 1023) / 1024;

    char* ws = (char*)d_ws;
    size_t off = 0;
    auto alloc = [&](size_t bytes) {
        char* p = ws + off;
        off += (bytes + 255) & ~(size_t)255;
        return p;
    };
    int*            cnt    = (int*)alloc((size_t)N * 4);
    int*            offs   = (int*)alloc((size_t)(N + 1) * 4);
    int*            cursor = (int*)alloc((size_t)N * 4);
    float*          dinv   = (float*)alloc((size_t)N * 4);
    int*            bsum   = (int*)alloc((size_t)NB * 4);
    int*            ssrc   = (int*)alloc((size_t)E * 4);
    float*          wsrc   = (float*)alloc((size_t)E * 4);
    unsigned short* wt1    = (unsigned short*)alloc((size_t)F1 * F0 * 2);
    unsigned short* wt2    = (unsigned short*)alloc((size_t)F2 * F1 * 2);
    unsigned char*  h1     = (unsigned char*)alloc((size_t)N * F1);      // fp8
    unsigned short* h1a    = (unsigned short*)alloc((size_t)N * F1 * 2); // bf16
    unsigned short* h2     = (unsigned short*)alloc((size_t)N * F2 * 2); // bf16
    (void)ws_size; (void)n_in; (void)out_size;

    // CSR build
    hipMemsetAsync(cnt, 0, (size_t)N * 4, stream);
    count_kernel_x<<<2048, 256, 0, stream>>>(dst, cnt, E, ng);
    scan_partial_kernel<<<NB, 256, 0, stream>>>(cnt, bsum, N);
    scan_finalize_kernel<<<NB, 256, 0, stream>>>(cnt, bsum, offs, dinv, cursor, N, NB);
    place_kernel_x<<<2048, 256, 0, stream>>>(src, dst, dinv, cursor, ssrc, wsrc, E, ng);

    // weights
    transpose_cast2_kernel<<<384, 64, 0, stream>>>(W1, wt1, W2, wt2);

    // layer 1: h1(fp8) = x @ W1 ; h1a(bf16) = relu(agg(h1))
    {
        dim3 grid((N + 127) / 128, F1 / 128);
        gemm_mfma_kernel<128, true, true><<<grid, 256, 0, stream>>>(x, wt1, h1, N, F0, F1);
    }
    agg_fp8_kernel<<<(N + 3) / 4, 256, 0, stream>>>(h1, dinv, offs, ssrc, wsrc, b1, h1a, N);

    // layer 2: h2(bf16) = h1a @ W2 ; out(fp32) = agg(h2)
    {
        dim3 grid((N + 127) / 128, F2 / 64);
        gemm_mfma_kernel<64, false, false><<<grid, 256, 0, stream>>>(h1a, wt2, h2, N, F1, F2);
    }
    agg_bf16_kernel<<<(N + 3) / 4, 256, 0, stream>>>(h2, dinv, offs, ssrc, wsrc, b2, out, N);
}